// Round 1
// baseline (4249.433 us; speedup 1.0000x reference)
//
#include <hip/hip_runtime.h>

#define NN 100000
#define NE 1600000
#define DIM 64

// agg = (1 + eps[l]) * x   (exact grid, float4)
__global__ __launch_bounds__(256) void k_init(const float* __restrict__ x,
                                              const float* __restrict__ eps, int l,
                                              float* __restrict__ agg) {
  float s = 1.0f + eps[l];
  int i = blockIdx.x * blockDim.x + threadIdx.x;
  const float4* x4 = (const float4*)x;
  float4* a4 = (float4*)agg;
  float4 v = x4[i];
  v.x *= s; v.y *= s; v.z *= s; v.w *= s;
  a4[i] = v;
}

// agg[dst] += x[src]  — 16 threads per edge, float4 gather + 4 atomics
__global__ __launch_bounds__(256) void k_scatter(const float* __restrict__ x,
                                                 const int* __restrict__ ei,
                                                 float* __restrict__ agg) {
  int t = blockIdx.x * blockDim.x + threadIdx.x;
  int e = t >> 4;
  int q = t & 15;
  int src = ei[e];
  int dst = ei[NE + e];
  float4 v = ((const float4*)(x + (size_t)src * DIM))[q];
  float* ap = agg + (size_t)dst * DIM + q * 4;
  atomicAdd(ap + 0, v.x);
  atomicAdd(ap + 1, v.y);
  atomicAdd(ap + 2, v.z);
  atomicAdd(ap + 3, v.w);
}

// out = relu(relu(in @ W1 + b1) @ W2 + b2)
// one wave per 64-node tile; lane = node-in-tile; acc[64] = full output row.
__global__ __launch_bounds__(64) void k_mlp(const float* __restrict__ in,
                                            const float* __restrict__ W1,
                                            const float* __restrict__ b1,
                                            const float* __restrict__ W2,
                                            const float* __restrict__ b2,
                                            float* __restrict__ out) {
  __shared__ float tile[64 * 65];  // +1 pad: (lane+k)%32 -> 2-way = free
  const int lane = threadIdx.x;
  const int base = blockIdx.x * 64;
  const int rows = min(64, NN - base);

  for (int r = 0; r < rows; ++r)
    tile[r * 65 + lane] = in[(size_t)(base + r) * DIM + lane];
  __syncthreads();

  float acc[64];
#pragma unroll
  for (int j = 0; j < 64; ++j) acc[j] = b1[j];
#pragma unroll 2
  for (int k = 0; k < 64; ++k) {
    float a = tile[lane * 65 + k];
#pragma unroll
    for (int j = 0; j < 64; ++j) acc[j] = fmaf(a, W1[k * 64 + j], acc[j]);
  }
  __syncthreads();
#pragma unroll
  for (int j = 0; j < 64; ++j) tile[lane * 65 + j] = fmaxf(acc[j], 0.0f);
  __syncthreads();

#pragma unroll
  for (int j = 0; j < 64; ++j) acc[j] = b2[j];
#pragma unroll 2
  for (int k = 0; k < 64; ++k) {
    float a = tile[lane * 65 + k];
#pragma unroll
    for (int j = 0; j < 64; ++j) acc[j] = fmaf(a, W2[k * 64 + j], acc[j]);
  }
  __syncthreads();
#pragma unroll
  for (int j = 0; j < 64; ++j) tile[lane * 65 + j] = fmaxf(acc[j], 0.0f);
  __syncthreads();

  for (int r = 0; r < rows; ++r)
    out[(size_t)(base + r) * DIM + lane] = tile[r * 65 + lane];
}

// out = in @ Wf + bf  (no relu; safe in-place per 64-row tile)
__global__ __launch_bounds__(64) void k_final(const float* __restrict__ in,
                                              const float* __restrict__ Wf,
                                              const float* __restrict__ bf,
                                              float* __restrict__ out) {
  __shared__ float tile[64 * 65];
  const int lane = threadIdx.x;
  const int base = blockIdx.x * 64;
  const int rows = min(64, NN - base);

  for (int r = 0; r < rows; ++r)
    tile[r * 65 + lane] = in[(size_t)(base + r) * DIM + lane];
  __syncthreads();

  float acc[64];
#pragma unroll
  for (int j = 0; j < 64; ++j) acc[j] = bf[j];
#pragma unroll 2
  for (int k = 0; k < 64; ++k) {
    float a = tile[lane * 65 + k];
#pragma unroll
    for (int j = 0; j < 64; ++j) acc[j] = fmaf(a, Wf[k * 64 + j], acc[j]);
  }
  __syncthreads();
#pragma unroll
  for (int j = 0; j < 64; ++j) tile[lane * 65 + j] = acc[j];
  __syncthreads();

  for (int r = 0; r < rows; ++r)
    out[(size_t)(base + r) * DIM + lane] = tile[r * 65 + lane];
}

extern "C" void kernel_launch(void* const* d_in, const int* in_sizes, int n_in,
                              void* d_out, int out_size, void* d_ws, size_t ws_size,
                              hipStream_t stream) {
  const float* x   = (const float*)d_in[0];
  const int*   ei  = (const int*)d_in[1];
  const float* W1  = (const float*)d_in[2];
  const float* b1  = (const float*)d_in[3];
  const float* W2  = (const float*)d_in[4];
  const float* b2  = (const float*)d_in[5];
  const float* eps = (const float*)d_in[6];
  const float* Wf  = (const float*)d_in[7];
  const float* bf  = (const float*)d_in[8];

  float* xb  = (float*)d_out;  // x lives in d_out after layer 1
  float* agg = (float*)d_ws;   // 100000*64*4 = 25.6 MB scratch

  const int grid_init    = NN * DIM / 4 / 256;  // 6250, exact
  const int grid_scatter = NE * 16 / 256;       // 100000, exact
  const int grid_mlp     = (NN + 63) / 64;      // 1563

  for (int l = 0; l < 3; ++l) {
    const float* xin = (l == 0) ? x : xb;
    k_init<<<grid_init, 256, 0, stream>>>(xin, eps, l, agg);
    k_scatter<<<grid_scatter, 256, 0, stream>>>(xin, ei, agg);
    k_mlp<<<grid_mlp, 64, 0, stream>>>(agg, W1 + (size_t)l * 64 * 64, b1 + (size_t)l * 64,
                                       W2 + (size_t)l * 64 * 64, b2 + (size_t)l * 64, xb);
  }
  k_final<<<grid_mlp, 64, 0, stream>>>(xb, Wf, bf, (float*)d_out);
}

// Round 3
// 1007.822 us; speedup vs baseline: 4.2165x; 4.2165x over previous
//
#include <hip/hip_runtime.h>

#define NN 100000
#define NE 1600000
#define DIM 64

// ---- CSR build ----

__global__ __launch_bounds__(256) void k_zero(int* __restrict__ deg) {
  int i = blockIdx.x * blockDim.x + threadIdx.x;
  if (i < NN) deg[i] = 0;
}

__global__ __launch_bounds__(256) void k_hist(const int* __restrict__ ei,
                                              int* __restrict__ deg) {
  int e = blockIdx.x * blockDim.x + threadIdx.x;
  atomicAdd(&deg[ei[NE + e]], 1);
}

// single-block exclusive scan of deg[NN] -> start, cursor
__global__ __launch_bounds__(1024) void k_scan(const int* __restrict__ deg,
                                               int* __restrict__ start,
                                               int* __restrict__ cursor) {
  __shared__ int buf[1024];
  const int t = threadIdx.x;
  const int CH = (NN + 1023) / 1024;  // 98
  const int lo = t * CH;
  const int hi = min(lo + CH, NN);
  int s = 0;
  for (int i = lo; i < hi; ++i) s += deg[i];
  buf[t] = s;
  __syncthreads();
  for (int off = 1; off < 1024; off <<= 1) {
    int u = (t >= off) ? buf[t - off] : 0;
    __syncthreads();
    buf[t] += u;
    __syncthreads();
  }
  int run = buf[t] - s;  // exclusive prefix of this chunk
  for (int i = lo; i < hi; ++i) {
    int d = deg[i];
    start[i] = run;
    cursor[i] = run;
    run += d;
  }
}

// scatter edge srcs into CSR slots; afterwards cursor[i] == end offset of node i
__global__ __launch_bounds__(256) void k_fill(const int* __restrict__ ei,
                                              int* __restrict__ cursor,
                                              int* __restrict__ csr) {
  int e = blockIdx.x * blockDim.x + threadIdx.x;
  int src = ei[e];
  int dst = ei[NE + e];
  int p = atomicAdd(&cursor[dst], 1);
  csr[p] = src;
}

// ---- fused layer: agg gather (CSR) -> LDS tile -> 2-layer MLP -> out ----
// RACE RULE: in and out must be DIFFERENT buffers (gather reads arbitrary rows
// of `x` while other blocks write their tiles of `out`).
__global__ __launch_bounds__(64) void k_gin(const float* __restrict__ x,
                                            const int* __restrict__ start,
                                            const int* __restrict__ end,
                                            const int* __restrict__ csr,
                                            const float* __restrict__ eps, int l,
                                            const float* __restrict__ W1,
                                            const float* __restrict__ b1,
                                            const float* __restrict__ W2,
                                            const float* __restrict__ b2,
                                            float* __restrict__ out) {
  __shared__ float tile[64 * 65];  // +1 pad: 2-way bank alias = free
  const int lane = threadIdx.x;
  const int base = blockIdx.x * 64;
  const int rows = min(64, NN - base);
  const float sc = 1.0f + eps[l];

  // phase 1: tile[n][lane] = (1+eps)*x[node] + sum_{e in N(node)} x[csr[e]]
  for (int n = 0; n < rows; ++n) {
    const int node = base + n;
    const int a = start[node], b = end[node];
    float a0 = sc * x[(size_t)node * DIM + lane];
    float a1 = 0.f, a2 = 0.f, a3 = 0.f;
    int e = a;
    for (; e + 3 < b; e += 4) {  // 4 outstanding row-loads for latency hiding
      int s0 = csr[e], s1 = csr[e + 1], s2 = csr[e + 2], s3 = csr[e + 3];
      a0 += x[(size_t)s0 * DIM + lane];
      a1 += x[(size_t)s1 * DIM + lane];
      a2 += x[(size_t)s2 * DIM + lane];
      a3 += x[(size_t)s3 * DIM + lane];
    }
    for (; e < b; ++e) a0 += x[(size_t)csr[e] * DIM + lane];
    tile[n * 65 + lane] = (a0 + a1) + (a2 + a3);
  }
  __syncthreads();

  // phase 2: MLP. lane owns node row; acc[64] = full output row (static idx only)
  float acc[64];
#pragma unroll
  for (int j = 0; j < 64; ++j) acc[j] = b1[j];
#pragma unroll 2
  for (int k = 0; k < 64; ++k) {
    float a = tile[lane * 65 + k];
#pragma unroll
    for (int j = 0; j < 64; ++j) acc[j] = fmaf(a, W1[k * 64 + j], acc[j]);
  }
  __syncthreads();
#pragma unroll
  for (int j = 0; j < 64; ++j) tile[lane * 65 + j] = fmaxf(acc[j], 0.0f);
  __syncthreads();

#pragma unroll
  for (int j = 0; j < 64; ++j) acc[j] = b2[j];
#pragma unroll 2
  for (int k = 0; k < 64; ++k) {
    float a = tile[lane * 65 + k];
#pragma unroll
    for (int j = 0; j < 64; ++j) acc[j] = fmaf(a, W2[k * 64 + j], acc[j]);
  }
  __syncthreads();
#pragma unroll
  for (int j = 0; j < 64; ++j) tile[lane * 65 + j] = fmaxf(acc[j], 0.0f);
  __syncthreads();

  for (int r = 0; r < rows; ++r)
    out[(size_t)(base + r) * DIM + lane] = tile[r * 65 + lane];
}

// out = in @ Wf + bf  (reads block-local rows only -> in==out would be safe,
// but here in and out are different buffers anyway)
__global__ __launch_bounds__(64) void k_final(const float* __restrict__ in,
                                              const float* __restrict__ Wf,
                                              const float* __restrict__ bf,
                                              float* __restrict__ out) {
  __shared__ float tile[64 * 65];
  const int lane = threadIdx.x;
  const int base = blockIdx.x * 64;
  const int rows = min(64, NN - base);

  for (int r = 0; r < rows; ++r)
    tile[r * 65 + lane] = in[(size_t)(base + r) * DIM + lane];
  __syncthreads();

  float acc[64];
#pragma unroll
  for (int j = 0; j < 64; ++j) acc[j] = bf[j];
#pragma unroll 2
  for (int k = 0; k < 64; ++k) {
    float a = tile[lane * 65 + k];
#pragma unroll
    for (int j = 0; j < 64; ++j) acc[j] = fmaf(a, Wf[k * 64 + j], acc[j]);
  }
  __syncthreads();
#pragma unroll
  for (int j = 0; j < 64; ++j) tile[lane * 65 + j] = acc[j];
  __syncthreads();

  for (int r = 0; r < rows; ++r)
    out[(size_t)(base + r) * DIM + lane] = tile[r * 65 + lane];
}

extern "C" void kernel_launch(void* const* d_in, const int* in_sizes, int n_in,
                              void* d_out, int out_size, void* d_ws, size_t ws_size,
                              hipStream_t stream) {
  const float* x   = (const float*)d_in[0];
  const int*   ei  = (const int*)d_in[1];
  const float* W1  = (const float*)d_in[2];
  const float* b1  = (const float*)d_in[3];
  const float* W2  = (const float*)d_in[4];
  const float* b2  = (const float*)d_in[5];
  const float* eps = (const float*)d_in[6];
  const float* Wf  = (const float*)d_in[7];
  const float* bf  = (const float*)d_in[8];

  float* xb = (float*)d_out;  // ping
  // ws layout: xc (float[NN*DIM], 25.6MB) | deg | start | cursor | csr  = 33.2MB
  float* xc = (float*)d_ws;   // pong
  int* deg    = (int*)(xc + (size_t)NN * DIM);
  int* startv = deg + NN;
  int* cursor = startv + NN;
  int* csr    = cursor + NN;

  const int grid_edges = NE / 256;       // 6250, exact
  const int grid_mlp   = (NN + 63) / 64; // 1563

  k_zero<<<(NN + 255) / 256, 256, 0, stream>>>(deg);
  k_hist<<<grid_edges, 256, 0, stream>>>(ei, deg);
  k_scan<<<1, 1024, 0, stream>>>(deg, startv, cursor);
  k_fill<<<grid_edges, 256, 0, stream>>>(ei, cursor, csr);  // cursor -> end offsets

  // ping-pong: L0 x->xc, L1 xc->xb, L2 xb->xc, final xc->xb
  k_gin<<<grid_mlp, 64, 0, stream>>>(x, startv, cursor, csr, eps, 0,
                                     W1, b1, W2, b2, xc);
  k_gin<<<grid_mlp, 64, 0, stream>>>(xc, startv, cursor, csr, eps, 1,
                                     W1 + 64 * 64, b1 + 64, W2 + 64 * 64, b2 + 64, xb);
  k_gin<<<grid_mlp, 64, 0, stream>>>(xb, startv, cursor, csr, eps, 2,
                                     W1 + 2 * 64 * 64, b1 + 2 * 64, W2 + 2 * 64 * 64, b2 + 2 * 64, xc);
  k_final<<<grid_mlp, 64, 0, stream>>>(xc, Wf, bf, xb);
}

// Round 4
// 890.246 us; speedup vs baseline: 4.7733x; 1.1321x over previous
//
#include <hip/hip_runtime.h>

#define NN 100000
#define NE 1600000
#define DIM 64
#define NB 391  // ceil(NN/256)

// ---- CSR build ----

__global__ __launch_bounds__(256) void k_zero(int* __restrict__ deg) {
  int i = blockIdx.x * blockDim.x + threadIdx.x;
  if (i < NN) deg[i] = 0;
}

__global__ __launch_bounds__(256) void k_hist(const int* __restrict__ ei,
                                              int* __restrict__ deg) {
  int e = blockIdx.x * blockDim.x + threadIdx.x;
  atomicAdd(&deg[ei[NE + e]], 1);
}

// phase 1: per-block exclusive scan of 256 elements -> start, block sums
__global__ __launch_bounds__(256) void k_scan1(const int* __restrict__ deg,
                                               int* __restrict__ start,
                                               int* __restrict__ bsum) {
  __shared__ int buf[256];
  const int t = threadIdx.x;
  const int i = blockIdx.x * 256 + t;
  int v = (i < NN) ? deg[i] : 0;
  buf[t] = v;
  __syncthreads();
  for (int off = 1; off < 256; off <<= 1) {
    int u = (t >= off) ? buf[t - off] : 0;
    __syncthreads();
    buf[t] += u;
    __syncthreads();
  }
  if (i < NN) start[i] = buf[t] - v;  // intra-block exclusive prefix
  if (t == 255) bsum[blockIdx.x] = buf[255];
}

// phase 2: single small block scans the NB block sums -> exclusive offsets
__global__ __launch_bounds__(512) void k_scan2(int* __restrict__ bsum,
                                               int* __restrict__ boff) {
  __shared__ int buf[512];
  const int t = threadIdx.x;
  int v = (t < NB) ? bsum[t] : 0;
  buf[t] = v;
  __syncthreads();
  for (int off = 1; off < 512; off <<= 1) {
    int u = (t >= off) ? buf[t - off] : 0;
    __syncthreads();
    buf[t] += u;
    __syncthreads();
  }
  if (t < NB) boff[t] = buf[t] - v;
}

// phase 3: add block offsets; init cursor
__global__ __launch_bounds__(256) void k_scan3(const int* __restrict__ boff,
                                               int* __restrict__ start,
                                               int* __restrict__ cursor) {
  int i = blockIdx.x * 256 + threadIdx.x;
  if (i < NN) {
    int s = start[i] + boff[blockIdx.x];
    start[i] = s;
    cursor[i] = s;
  }
}

// scatter edge srcs into CSR slots; afterwards cursor[i] == end offset of node i
__global__ __launch_bounds__(256) void k_fill(const int* __restrict__ ei,
                                              int* __restrict__ cursor,
                                              int* __restrict__ csr) {
  int e = blockIdx.x * blockDim.x + threadIdx.x;
  int src = ei[e];
  int dst = ei[NE + e];
  int p = atomicAdd(&cursor[dst], 1);
  csr[p] = src;
}

// ---- fused layer: CSR gather -> LDS tile -> 2-layer MLP -> out ----
// 256 threads = 4 waves per 64-node tile. Gather rows interleaved across waves
// (4x outstanding loads); MLP: each wave owns 16 output columns (acc[16]).
// RACE RULE: in and out must be DIFFERENT buffers.
__global__ __launch_bounds__(256) void k_gin(const float* __restrict__ x,
                                             const int* __restrict__ start,
                                             const int* __restrict__ end,
                                             const int* __restrict__ csr,
                                             const float* __restrict__ eps, int l,
                                             const float* __restrict__ W1,
                                             const float* __restrict__ b1,
                                             const float* __restrict__ W2,
                                             const float* __restrict__ b2,
                                             float* __restrict__ out) {
  __shared__ float tile[64 * 65];  // +1 pad: 2-way bank alias = free
  const int lane = threadIdx.x & 63;
  const int wv = threadIdx.x >> 6;  // 0..3
  const int base = blockIdx.x * 64;
  const int rows = min(64, NN - base);
  const float sc = 1.0f + eps[l];
  const int jc = wv * 16;  // this wave's output-column base

  // phase 1: gather. wave wv handles rows wv, wv+4, ...
  for (int n = wv; n < rows; n += 4) {
    const int node = base + n;
    const int a = start[node], b = end[node];
    float a0 = sc * x[(size_t)node * DIM + lane];
    float a1 = 0.f, a2 = 0.f, a3 = 0.f;
    int e = a;
    for (; e + 3 < b; e += 4) {
      int s0 = csr[e], s1 = csr[e + 1], s2 = csr[e + 2], s3 = csr[e + 3];
      a0 += x[(size_t)s0 * DIM + lane];
      a1 += x[(size_t)s1 * DIM + lane];
      a2 += x[(size_t)s2 * DIM + lane];
      a3 += x[(size_t)s3 * DIM + lane];
    }
    for (; e < b; ++e) a0 += x[(size_t)csr[e] * DIM + lane];
    tile[n * 65 + lane] = (a0 + a1) + (a2 + a3);
  }
  __syncthreads();

  // phase 2: GEMM1. lane = node row; wave owns cols [jc, jc+16)
  float acc[16];
#pragma unroll
  for (int j = 0; j < 16; ++j) acc[j] = b1[jc + j];
#pragma unroll 4
  for (int k = 0; k < 64; ++k) {
    float a = tile[lane * 65 + k];
#pragma unroll
    for (int j = 0; j < 16; ++j) acc[j] = fmaf(a, W1[k * 64 + jc + j], acc[j]);
  }
  __syncthreads();  // everyone done READING tile before overwrite
#pragma unroll
  for (int j = 0; j < 16; ++j) tile[lane * 65 + jc + j] = fmaxf(acc[j], 0.0f);
  __syncthreads();

  // GEMM2
#pragma unroll
  for (int j = 0; j < 16; ++j) acc[j] = b2[jc + j];
#pragma unroll 4
  for (int k = 0; k < 64; ++k) {
    float a = tile[lane * 65 + k];
#pragma unroll
    for (int j = 0; j < 16; ++j) acc[j] = fmaf(a, W2[k * 64 + jc + j], acc[j]);
  }
  __syncthreads();
#pragma unroll
  for (int j = 0; j < 16; ++j) tile[lane * 65 + jc + j] = fmaxf(acc[j], 0.0f);
  __syncthreads();

  for (int n = wv; n < rows; n += 4)
    out[(size_t)(base + n) * DIM + lane] = tile[n * 65 + lane];
}

// out = in @ Wf + bf  (no relu)
__global__ __launch_bounds__(256) void k_final(const float* __restrict__ in,
                                               const float* __restrict__ Wf,
                                               const float* __restrict__ bf,
                                               float* __restrict__ out) {
  __shared__ float tile[64 * 65];
  const int lane = threadIdx.x & 63;
  const int wv = threadIdx.x >> 6;
  const int base = blockIdx.x * 64;
  const int rows = min(64, NN - base);
  const int jc = wv * 16;

  for (int n = wv; n < rows; n += 4)
    tile[n * 65 + lane] = in[(size_t)(base + n) * DIM + lane];
  __syncthreads();

  float acc[16];
#pragma unroll
  for (int j = 0; j < 16; ++j) acc[j] = bf[jc + j];
#pragma unroll 4
  for (int k = 0; k < 64; ++k) {
    float a = tile[lane * 65 + k];
#pragma unroll
    for (int j = 0; j < 16; ++j) acc[j] = fmaf(a, Wf[k * 64 + jc + j], acc[j]);
  }
  __syncthreads();
#pragma unroll
  for (int j = 0; j < 16; ++j) tile[lane * 65 + jc + j] = acc[j];
  __syncthreads();

  for (int n = wv; n < rows; n += 4)
    out[(size_t)(base + n) * DIM + lane] = tile[n * 65 + lane];
}

extern "C" void kernel_launch(void* const* d_in, const int* in_sizes, int n_in,
                              void* d_out, int out_size, void* d_ws, size_t ws_size,
                              hipStream_t stream) {
  const float* x   = (const float*)d_in[0];
  const int*   ei  = (const int*)d_in[1];
  const float* W1  = (const float*)d_in[2];
  const float* b1  = (const float*)d_in[3];
  const float* W2  = (const float*)d_in[4];
  const float* b2  = (const float*)d_in[5];
  const float* eps = (const float*)d_in[6];
  const float* Wf  = (const float*)d_in[7];
  const float* bf  = (const float*)d_in[8];

  float* xb = (float*)d_out;  // ping
  // ws: xc (25.6MB) | deg | start | cursor | csr | bsum | boff  (~33.2MB)
  float* xc = (float*)d_ws;   // pong
  int* deg    = (int*)(xc + (size_t)NN * DIM);
  int* startv = deg + NN;
  int* cursor = startv + NN;
  int* csr    = cursor + NN;
  int* bsum   = csr + NE;
  int* boff   = bsum + NB;

  const int grid_edges = NE / 256;       // 6250, exact
  const int grid_mlp   = (NN + 63) / 64; // 1563

  k_zero<<<NB, 256, 0, stream>>>(deg);
  k_hist<<<grid_edges, 256, 0, stream>>>(ei, deg);
  k_scan1<<<NB, 256, 0, stream>>>(deg, startv, bsum);
  k_scan2<<<1, 512, 0, stream>>>(bsum, boff);
  k_scan3<<<NB, 256, 0, stream>>>(boff, startv, cursor);
  k_fill<<<grid_edges, 256, 0, stream>>>(ei, cursor, csr);  // cursor -> end

  // ping-pong: L0 x->xc, L1 xc->xb, L2 xb->xc, final xc->xb
  k_gin<<<grid_mlp, 256, 0, stream>>>(x, startv, cursor, csr, eps, 0,
                                      W1, b1, W2, b2, xc);
  k_gin<<<grid_mlp, 256, 0, stream>>>(xc, startv, cursor, csr, eps, 1,
                                      W1 + 64 * 64, b1 + 64, W2 + 64 * 64, b2 + 64, xb);
  k_gin<<<grid_mlp, 256, 0, stream>>>(xb, startv, cursor, csr, eps, 2,
                                      W1 + 2 * 64 * 64, b1 + 2 * 64, W2 + 2 * 64 * 64, b2 + 2 * 64, xc);
  k_final<<<grid_mlp, 256, 0, stream>>>(xc, Wf, bf, xb);
}

// Round 5
// 867.907 us; speedup vs baseline: 4.8962x; 1.0257x over previous
//
#include <hip/hip_runtime.h>

#define NN 100000
#define NE 1600000
#define DIM 64
#define NB 391  // ceil(NN/256)

typedef unsigned short u16;

__device__ __forceinline__ u16 f2b(float f) {  // f32 -> bf16 RNE
  union { float f; unsigned u; } c; c.f = f;
  unsigned u = c.u;
  u += 0x7FFF + ((u >> 16) & 1);
  return (u16)(u >> 16);
}
__device__ __forceinline__ float b2f(u16 h) {
  union { unsigned u; float f; } c; c.u = ((unsigned)h) << 16;
  return c.f;
}

// x (f32) -> xh (bf16), 4 elems/thread, exact grid
__global__ __launch_bounds__(256) void k_tobf(const float* __restrict__ x,
                                              u16* __restrict__ xh) {
  int i = blockIdx.x * 256 + threadIdx.x;
  float4 v = ((const float4*)x)[i];
  ushort4 o;
  o.x = f2b(v.x); o.y = f2b(v.y); o.z = f2b(v.z); o.w = f2b(v.w);
  ((ushort4*)xh)[i] = o;
}

// ---- CSR build ----

__global__ __launch_bounds__(256) void k_zero(int* __restrict__ deg) {
  int i = blockIdx.x * blockDim.x + threadIdx.x;
  if (i < NN) deg[i] = 0;
}

__global__ __launch_bounds__(256) void k_hist(const int* __restrict__ ei,
                                              int* __restrict__ deg) {
  int e = blockIdx.x * blockDim.x + threadIdx.x;
  atomicAdd(&deg[ei[NE + e]], 1);
}

__global__ __launch_bounds__(256) void k_scan1(const int* __restrict__ deg,
                                               int* __restrict__ start,
                                               int* __restrict__ bsum) {
  __shared__ int buf[256];
  const int t = threadIdx.x;
  const int i = blockIdx.x * 256 + t;
  int v = (i < NN) ? deg[i] : 0;
  buf[t] = v;
  __syncthreads();
  for (int off = 1; off < 256; off <<= 1) {
    int u = (t >= off) ? buf[t - off] : 0;
    __syncthreads();
    buf[t] += u;
    __syncthreads();
  }
  if (i < NN) start[i] = buf[t] - v;
  if (t == 255) bsum[blockIdx.x] = buf[255];
}

__global__ __launch_bounds__(512) void k_scan2(int* __restrict__ bsum,
                                               int* __restrict__ boff) {
  __shared__ int buf[512];
  const int t = threadIdx.x;
  int v = (t < NB) ? bsum[t] : 0;
  buf[t] = v;
  __syncthreads();
  for (int off = 1; off < 512; off <<= 1) {
    int u = (t >= off) ? buf[t - off] : 0;
    __syncthreads();
    buf[t] += u;
    __syncthreads();
  }
  if (t < NB) boff[t] = buf[t] - v;
}

__global__ __launch_bounds__(256) void k_scan3(const int* __restrict__ boff,
                                               int* __restrict__ start,
                                               int* __restrict__ cursor) {
  int i = blockIdx.x * 256 + threadIdx.x;
  if (i < NN) {
    int s = start[i] + boff[blockIdx.x];
    start[i] = s;
    cursor[i] = s;
  }
}

__global__ __launch_bounds__(256) void k_fill(const int* __restrict__ ei,
                                              int* __restrict__ cursor,
                                              int* __restrict__ csr) {
  int e = blockIdx.x * blockDim.x + threadIdx.x;
  int src = ei[e];
  int dst = ei[NE + e];
  int p = atomicAdd(&cursor[dst], 1);
  csr[p] = src;
}

// ---- fused layer: bf16 CSR gather -> f32 LDS tile -> MLP -> bf16 out ----
// 4 waves per 64-node tile; gather rows interleaved across waves, 8-deep unroll.
// RACE RULE: xh-in and xh-out must be DIFFERENT buffers.
__global__ __launch_bounds__(256) void k_gin(const u16* __restrict__ xh,
                                             const int* __restrict__ start,
                                             const int* __restrict__ end,
                                             const int* __restrict__ csr,
                                             const float* __restrict__ eps, int l,
                                             const float* __restrict__ W1,
                                             const float* __restrict__ b1,
                                             const float* __restrict__ W2,
                                             const float* __restrict__ b2,
                                             u16* __restrict__ outh) {
  __shared__ float tile[64 * 65];
  const int lane = threadIdx.x & 63;
  const int wv = threadIdx.x >> 6;
  const int base = blockIdx.x * 64;
  const int rows = min(64, NN - base);
  const float sc = 1.0f + eps[l];
  const int jc = wv * 16;

  // phase 1: gather (8 independent row-loads in flight)
  for (int n = wv; n < rows; n += 4) {
    const int node = base + n;
    int e = start[node];
    const int bnd = end[node];
    float a0 = sc * b2f(xh[(size_t)node * DIM + lane]);
    float a1 = 0.f, a2 = 0.f, a3 = 0.f, a4 = 0.f, a5 = 0.f, a6 = 0.f, a7 = 0.f;
    for (; e + 7 < bnd; e += 8) {
      int s0 = csr[e],     s1 = csr[e + 1], s2 = csr[e + 2], s3 = csr[e + 3];
      int s4 = csr[e + 4], s5 = csr[e + 5], s6 = csr[e + 6], s7 = csr[e + 7];
      u16 h0 = xh[(size_t)s0 * DIM + lane];
      u16 h1 = xh[(size_t)s1 * DIM + lane];
      u16 h2 = xh[(size_t)s2 * DIM + lane];
      u16 h3 = xh[(size_t)s3 * DIM + lane];
      u16 h4 = xh[(size_t)s4 * DIM + lane];
      u16 h5 = xh[(size_t)s5 * DIM + lane];
      u16 h6 = xh[(size_t)s6 * DIM + lane];
      u16 h7 = xh[(size_t)s7 * DIM + lane];
      a0 += b2f(h0); a1 += b2f(h1); a2 += b2f(h2); a3 += b2f(h3);
      a4 += b2f(h4); a5 += b2f(h5); a6 += b2f(h6); a7 += b2f(h7);
    }
    for (; e < bnd; ++e) a0 += b2f(xh[(size_t)csr[e] * DIM + lane]);
    tile[n * 65 + lane] = ((a0 + a1) + (a2 + a3)) + ((a4 + a5) + (a6 + a7));
  }
  __syncthreads();

  // phase 2: GEMM1 (f32). lane = node row; wave owns cols [jc, jc+16)
  float acc[16];
#pragma unroll
  for (int j = 0; j < 16; ++j) acc[j] = b1[jc + j];
#pragma unroll 4
  for (int k = 0; k < 64; ++k) {
    float a = tile[lane * 65 + k];
#pragma unroll
    for (int j = 0; j < 16; ++j) acc[j] = fmaf(a, W1[k * 64 + jc + j], acc[j]);
  }
  __syncthreads();
#pragma unroll
  for (int j = 0; j < 16; ++j) tile[lane * 65 + jc + j] = fmaxf(acc[j], 0.0f);
  __syncthreads();

  // GEMM2
#pragma unroll
  for (int j = 0; j < 16; ++j) acc[j] = b2[jc + j];
#pragma unroll 4
  for (int k = 0; k < 64; ++k) {
    float a = tile[lane * 65 + k];
#pragma unroll
    for (int j = 0; j < 16; ++j) acc[j] = fmaf(a, W2[k * 64 + jc + j], acc[j]);
  }
  __syncthreads();
#pragma unroll
  for (int j = 0; j < 16; ++j) tile[lane * 65 + jc + j] = fmaxf(acc[j], 0.0f);
  __syncthreads();

  for (int n = wv; n < rows; n += 4)
    outh[(size_t)(base + n) * DIM + lane] = f2b(tile[n * 65 + lane]);
}

// out(f32) = bf16_in @ Wf + bf
__global__ __launch_bounds__(256) void k_final(const u16* __restrict__ in,
                                               const float* __restrict__ Wf,
                                               const float* __restrict__ bf,
                                               float* __restrict__ out) {
  __shared__ float tile[64 * 65];
  const int lane = threadIdx.x & 63;
  const int wv = threadIdx.x >> 6;
  const int base = blockIdx.x * 64;
  const int rows = min(64, NN - base);
  const int jc = wv * 16;

  for (int n = wv; n < rows; n += 4)
    tile[n * 65 + lane] = b2f(in[(size_t)(base + n) * DIM + lane]);
  __syncthreads();

  float acc[16];
#pragma unroll
  for (int j = 0; j < 16; ++j) acc[j] = bf[jc + j];
#pragma unroll 4
  for (int k = 0; k < 64; ++k) {
    float a = tile[lane * 65 + k];
#pragma unroll
    for (int j = 0; j < 16; ++j) acc[j] = fmaf(a, Wf[k * 64 + jc + j], acc[j]);
  }
  __syncthreads();
#pragma unroll
  for (int j = 0; j < 16; ++j) tile[lane * 65 + jc + j] = acc[j];
  __syncthreads();

  for (int n = wv; n < rows; n += 4)
    out[(size_t)(base + n) * DIM + lane] = tile[n * 65 + lane];
}

extern "C" void kernel_launch(void* const* d_in, const int* in_sizes, int n_in,
                              void* d_out, int out_size, void* d_ws, size_t ws_size,
                              hipStream_t stream) {
  const float* x   = (const float*)d_in[0];
  const int*   ei  = (const int*)d_in[1];
  const float* W1  = (const float*)d_in[2];
  const float* b1  = (const float*)d_in[3];
  const float* W2  = (const float*)d_in[4];
  const float* b2  = (const float*)d_in[5];
  const float* eps = (const float*)d_in[6];
  const float* Wf  = (const float*)d_in[7];
  const float* bf  = (const float*)d_in[8];

  // ws: xh0 (12.8MB) | xh1 (12.8MB) | deg | start | cursor | csr | bsum | boff
  u16* xh0 = (u16*)d_ws;
  u16* xh1 = xh0 + (size_t)NN * DIM;
  int* deg    = (int*)(xh1 + (size_t)NN * DIM);
  int* startv = deg + NN;
  int* cursor = startv + NN;
  int* csr    = cursor + NN;
  int* bsum   = csr + NE;
  int* boff   = bsum + NB;

  const int grid_edges = NE / 256;       // 6250, exact
  const int grid_conv  = NN * DIM / 4 / 256;  // 6250, exact
  const int grid_mlp   = (NN + 63) / 64; // 1563

  k_tobf<<<grid_conv, 256, 0, stream>>>(x, xh0);
  k_zero<<<NB, 256, 0, stream>>>(deg);
  k_hist<<<grid_edges, 256, 0, stream>>>(ei, deg);
  k_scan1<<<NB, 256, 0, stream>>>(deg, startv, bsum);
  k_scan2<<<1, 512, 0, stream>>>(bsum, boff);
  k_scan3<<<NB, 256, 0, stream>>>(boff, startv, cursor);
  k_fill<<<grid_edges, 256, 0, stream>>>(ei, cursor, csr);  // cursor -> end

  // bf16 ping-pong: L0 xh0->xh1, L1 xh1->xh0, L2 xh0->xh1, final xh1->d_out
  k_gin<<<grid_mlp, 256, 0, stream>>>(xh0, startv, cursor, csr, eps, 0,
                                      W1, b1, W2, b2, xh1);
  k_gin<<<grid_mlp, 256, 0, stream>>>(xh1, startv, cursor, csr, eps, 1,
                                      W1 + 64 * 64, b1 + 64, W2 + 64 * 64, b2 + 64, xh0);
  k_gin<<<grid_mlp, 256, 0, stream>>>(xh0, startv, cursor, csr, eps, 2,
                                      W1 + 2 * 64 * 64, b1 + 2 * 64, W2 + 2 * 64 * 64, b2 + 2 * 64, xh1);
  k_final<<<grid_mlp, 256, 0, stream>>>(xh1, Wf, bf, (float*)d_out);
}

// Round 6
// 517.710 us; speedup vs baseline: 8.2081x; 1.6764x over previous
//
#include <hip/hip_runtime.h>

#define NN 100000
#define NE 1600000
#define DIM 64
#define NB 391      // ceil(NN/256)
#define IDXCAP 2048 // staged csr indices per block (typ ~1056)

typedef unsigned short u16;
typedef unsigned int u32;

__device__ __forceinline__ u16 f2b(float f) {  // f32 -> bf16 RNE
  union { float f; u32 u; } c; c.f = f;
  u32 u = c.u;
  u += 0x7FFF + ((u >> 16) & 1);
  return (u16)(u >> 16);
}
__device__ __forceinline__ float b2f(u16 h) {
  union { u32 u; float f; } c; c.u = ((u32)h) << 16;
  return c.f;
}
__device__ __forceinline__ float blo(u32 v) {  // low bf16 of packed pair
  union { u32 u; float f; } c; c.u = v << 16;
  return c.f;
}
__device__ __forceinline__ float bhi(u32 v) {  // high bf16 of packed pair
  union { u32 u; float f; } c; c.u = v & 0xFFFF0000u;
  return c.f;
}

// x (f32) -> xh (bf16), 4 elems/thread, exact grid (rows 0..NN-1)
__global__ __launch_bounds__(256) void k_tobf(const float* __restrict__ x,
                                              u16* __restrict__ xh) {
  int i = blockIdx.x * 256 + threadIdx.x;
  float4 v = ((const float4*)x)[i];
  ushort4 o;
  o.x = f2b(v.x); o.y = f2b(v.y); o.z = f2b(v.z); o.w = f2b(v.w);
  ((ushort4*)xh)[i] = o;
}

// zero the dummy row NN of both bf16 buffers (pad edges gather zeros)
__global__ __launch_bounds__(128) void k_zrow(u16* __restrict__ a,
                                              u16* __restrict__ b) {
  int t = threadIdx.x;
  if (t < 64) a[(size_t)NN * DIM + t] = 0;
  else        b[(size_t)NN * DIM + (t - 64)] = 0;
}

// ---- CSR build (degrees padded to even; dummy src = NN) ----

__global__ __launch_bounds__(256) void k_zero(int* __restrict__ deg) {
  int i = blockIdx.x * blockDim.x + threadIdx.x;
  if (i < NN) deg[i] = 0;
}

__global__ __launch_bounds__(256) void k_hist(const int* __restrict__ ei,
                                              int* __restrict__ deg) {
  int e = blockIdx.x * blockDim.x + threadIdx.x;
  atomicAdd(&deg[ei[NE + e]], 1);
}

// per-block exclusive scan of PADDED degrees -> start, block sums
__global__ __launch_bounds__(256) void k_scan1(const int* __restrict__ deg,
                                               int* __restrict__ start,
                                               int* __restrict__ bsum) {
  __shared__ int buf[256];
  const int t = threadIdx.x;
  const int i = blockIdx.x * 256 + t;
  int v = (i < NN) ? ((deg[i] + 1) & ~1) : 0;
  buf[t] = v;
  __syncthreads();
  for (int off = 1; off < 256; off <<= 1) {
    int u = (t >= off) ? buf[t - off] : 0;
    __syncthreads();
    buf[t] += u;
    __syncthreads();
  }
  if (i < NN) start[i] = buf[t] - v;
  if (t == 255) bsum[blockIdx.x] = buf[255];
}

__global__ __launch_bounds__(512) void k_scan2(int* __restrict__ bsum,
                                               int* __restrict__ boff) {
  __shared__ int buf[512];
  const int t = threadIdx.x;
  int v = (t < NB) ? bsum[t] : 0;
  buf[t] = v;
  __syncthreads();
  for (int off = 1; off < 512; off <<= 1) {
    int u = (t >= off) ? buf[t - off] : 0;
    __syncthreads();
    buf[t] += u;
    __syncthreads();
  }
  if (t < NB) boff[t] = buf[t] - v;
}

// add block offsets; init cursor (cursor buffer ALIASES deg -> read deg first).
// thread NN-1 also writes start[NN] = total padded edges.
__global__ __launch_bounds__(256) void k_scan3(const int* __restrict__ boff,
                                               int* start, int* cur) {
  int i = blockIdx.x * 256 + threadIdx.x;
  if (i < NN) {
    int d = cur[i];  // old deg (aliased buffer)
    int s = start[i] + boff[blockIdx.x];
    start[i] = s;
    cur[i] = s;
    if (i == NN - 1) start[NN] = s + ((d + 1) & ~1);
  }
}

__global__ __launch_bounds__(256) void k_fill(const int* __restrict__ ei,
                                              int* __restrict__ cursor,
                                              int* __restrict__ csr) {
  int e = blockIdx.x * blockDim.x + threadIdx.x;
  int src = ei[e];
  int dst = ei[NE + e];
  int p = atomicAdd(&cursor[dst], 1);
  csr[p] = src;
}

// fill the <=1 pad slot per node with dummy node NN
__global__ __launch_bounds__(256) void k_pad(const int* __restrict__ cursor,
                                             const int* __restrict__ start,
                                             int* __restrict__ csr) {
  int i = blockIdx.x * 256 + threadIdx.x;
  if (i < NN) {
    int c = cursor[i];
    if (c < start[i + 1]) csr[c] = NN;
  }
}

// ---- fused layer: LDS-staged-idx bf16 gather (2 edges/load) -> MLP ----
// 4 waves per 64-node tile. Per row: lanes 0-31 = even edges, 32-63 = odd
// edges; each lane accumulates feature pair {2fl, 2fl+1}; halves combined
// with one shfl_xor(32). RACE RULE: xh-in and xh-out differ.
__global__ __launch_bounds__(256) void k_gin(const u16* __restrict__ xh,
                                             const int* __restrict__ startP,
                                             const int* __restrict__ csr,
                                             const float* __restrict__ eps, int l,
                                             const float* __restrict__ W1,
                                             const float* __restrict__ b1,
                                             const float* __restrict__ W2,
                                             const float* __restrict__ b2,
                                             u16* __restrict__ outh) {
  __shared__ float tile[64 * 65];
  __shared__ int sidx[IDXCAP];
  const int tid = threadIdx.x;
  const int lane = tid & 63;
  const int wv = tid >> 6;
  const int h = lane >> 5;   // half id
  const int fl = lane & 31;  // feature-pair id
  const int base = blockIdx.x * 64;
  const int rows = min(64, NN - base);
  const float sc = 1.0f + eps[l];
  const float sch = (lane < 32) ? sc : 0.0f;  // self term only in half 0
  const u32* xu = (const u32*)xh;

  // stage this block's contiguous csr slice into LDS (coalesced)
  const int s0 = startP[base];
  const int cnt = startP[base + rows] - s0;
  const int cs = min(cnt, IDXCAP);
  for (int p = tid; p < cs; p += 256) sidx[p] = csr[s0 + p];
  __syncthreads();

  for (int n = wv; n < rows; n += 4) {
    const int node = base + n;
    const int a = startP[node] - s0;
    const int bnd = startP[node + 1] - s0;
    const int m = (bnd - a) >> 1;  // per-half edge count (padded even)
    const int off = a + h;
    u32 us = xu[node * 32 + fl];
    float p0 = sch * blo(us), p1 = sch * bhi(us);
    float q0 = 0.f, q1 = 0.f, r0 = 0.f, r1 = 0.f, d0 = 0.f, d1 = 0.f;
    float t0 = 0.f, t1 = 0.f, v0 = 0.f, v1 = 0.f, w0 = 0.f, w1 = 0.f;
    float g0 = 0.f, g1 = 0.f, y0 = 0.f, y1 = 0.f;
    int i = 0;
    if (bnd <= cs) {  // fast path: indices in LDS (16 edges in flight)
      for (; i + 7 < m; i += 8) {
        int i0 = sidx[off + 2 * i],      i1 = sidx[off + 2 * i + 2];
        int i2 = sidx[off + 2 * i + 4],  i3 = sidx[off + 2 * i + 6];
        int i4 = sidx[off + 2 * i + 8],  i5 = sidx[off + 2 * i + 10];
        int i6 = sidx[off + 2 * i + 12], i7 = sidx[off + 2 * i + 14];
        u32 u0 = xu[(size_t)i0 * 32 + fl], u1 = xu[(size_t)i1 * 32 + fl];
        u32 u2 = xu[(size_t)i2 * 32 + fl], u3 = xu[(size_t)i3 * 32 + fl];
        u32 u4 = xu[(size_t)i4 * 32 + fl], u5 = xu[(size_t)i5 * 32 + fl];
        u32 u6 = xu[(size_t)i6 * 32 + fl], u7 = xu[(size_t)i7 * 32 + fl];
        p0 += blo(u0); p1 += bhi(u0); q0 += blo(u1); q1 += bhi(u1);
        r0 += blo(u2); r1 += bhi(u2); d0 += blo(u3); d1 += bhi(u3);
        t0 += blo(u4); t1 += bhi(u4); v0 += blo(u5); v1 += bhi(u5);
        w0 += blo(u6); w1 += bhi(u6); g0 += blo(u7); g1 += bhi(u7);
      }
      for (; i < m; ++i) {
        int ix = sidx[off + 2 * i];
        u32 u = xu[(size_t)ix * 32 + fl];
        y0 += blo(u); y1 += bhi(u);
      }
    } else {  // slow path (statistically never): global csr reads
      for (; i < m; ++i) {
        int ix = csr[s0 + off + 2 * i];
        u32 u = xu[(size_t)ix * 32 + fl];
        y0 += blo(u); y1 += bhi(u);
      }
    }
    float e0 = (((p0 + q0) + (r0 + d0)) + ((t0 + v0) + (w0 + g0))) + y0;
    float e1 = (((p1 + q1) + (r1 + d1)) + ((t1 + v1) + (w1 + g1))) + y1;
    e0 += __shfl_xor(e0, 32, 64);
    e1 += __shfl_xor(e1, 32, 64);
    if (lane < 32) {
      tile[n * 65 + 2 * fl] = e0;
      tile[n * 65 + 2 * fl + 1] = e1;
    }
  }
  __syncthreads();

  // MLP. lane = node row; wave owns cols [jcs, jcs+16). jcs in SGPR so
  // W/bias loads become scalar.
  const int jcs = __builtin_amdgcn_readfirstlane(wv * 16);
  float acc[16];
#pragma unroll
  for (int j = 0; j < 16; ++j) acc[j] = b1[jcs + j];
#pragma unroll 4
  for (int k = 0; k < 64; ++k) {
    float a = tile[lane * 65 + k];
#pragma unroll
    for (int j = 0; j < 16; ++j) acc[j] = fmaf(a, W1[k * 64 + jcs + j], acc[j]);
  }
  __syncthreads();
#pragma unroll
  for (int j = 0; j < 16; ++j) tile[lane * 65 + jcs + j] = fmaxf(acc[j], 0.0f);
  __syncthreads();

#pragma unroll
  for (int j = 0; j < 16; ++j) acc[j] = b2[jcs + j];
#pragma unroll 4
  for (int k = 0; k < 64; ++k) {
    float a = tile[lane * 65 + k];
#pragma unroll
    for (int j = 0; j < 16; ++j) acc[j] = fmaf(a, W2[k * 64 + jcs + j], acc[j]);
  }
  __syncthreads();
#pragma unroll
  for (int j = 0; j < 16; ++j) tile[lane * 65 + jcs + j] = fmaxf(acc[j], 0.0f);
  __syncthreads();

  for (int n = wv; n < rows; n += 4)
    outh[(size_t)(base + n) * DIM + lane] = f2b(tile[n * 65 + lane]);
}

// out(f32) = bf16_in @ Wf + bf
__global__ __launch_bounds__(256) void k_final(const u16* __restrict__ in,
                                               const float* __restrict__ Wf,
                                               const float* __restrict__ bf,
                                               float* __restrict__ out) {
  __shared__ float tile[64 * 65];
  const int lane = threadIdx.x & 63;
  const int wv = threadIdx.x >> 6;
  const int base = blockIdx.x * 64;
  const int rows = min(64, NN - base);
  const int jcs = __builtin_amdgcn_readfirstlane(wv * 16);

  for (int n = wv; n < rows; n += 4)
    tile[n * 65 + lane] = b2f(in[(size_t)(base + n) * DIM + lane]);
  __syncthreads();

  float acc[16];
#pragma unroll
  for (int j = 0; j < 16; ++j) acc[j] = bf[jcs + j];
#pragma unroll 4
  for (int k = 0; k < 64; ++k) {
    float a = tile[lane * 65 + k];
#pragma unroll
    for (int j = 0; j < 16; ++j) acc[j] = fmaf(a, Wf[k * 64 + jcs + j], acc[j]);
  }
  __syncthreads();
#pragma unroll
  for (int j = 0; j < 16; ++j) tile[lane * 65 + jcs + j] = acc[j];
  __syncthreads();

  for (int n = wv; n < rows; n += 4)
    out[(size_t)(base + n) * DIM + lane] = tile[n * 65 + lane];
}

extern "C" void kernel_launch(void* const* d_in, const int* in_sizes, int n_in,
                              void* d_out, int out_size, void* d_ws, size_t ws_size,
                              hipStream_t stream) {
  const float* x   = (const float*)d_in[0];
  const int*   ei  = (const int*)d_in[1];
  const float* W1  = (const float*)d_in[2];
  const float* b1  = (const float*)d_in[3];
  const float* W2  = (const float*)d_in[4];
  const float* b2  = (const float*)d_in[5];
  const float* eps = (const float*)d_in[6];
  const float* Wf  = (const float*)d_in[7];
  const float* bf  = (const float*)d_in[8];

  // ws: xh0[(NN+1)*64] | xh1[(NN+1)*64] (u16) | startP[NN+1] | degcur[NN]
  //     | csr[NE+NN] | bsum[NB] | boff[NB]   (~33.2 MB)
  u16* xh0 = (u16*)d_ws;
  u16* xh1 = xh0 + (size_t)(NN + 1) * DIM;
  int* startP = (int*)(xh1 + (size_t)(NN + 1) * DIM);
  int* degcur = startP + NN + 1;  // deg during build, then cursor (aliased)
  int* csr    = degcur + NN;
  int* bsum   = csr + NE + NN;
  int* boff   = bsum + NB;

  const int grid_edges = NE / 256;            // 6250, exact
  const int grid_conv  = NN * DIM / 4 / 256;  // 6250, exact
  const int grid_node  = (NN + 255) / 256;    // 391
  const int grid_mlp   = (NN + 63) / 64;      // 1563

  k_tobf<<<grid_conv, 256, 0, stream>>>(x, xh0);
  k_zrow<<<1, 128, 0, stream>>>(xh0, xh1);
  k_zero<<<grid_node, 256, 0, stream>>>(degcur);
  k_hist<<<grid_edges, 256, 0, stream>>>(ei, degcur);
  k_scan1<<<grid_node, 256, 0, stream>>>(degcur, startP, bsum);
  k_scan2<<<1, 512, 0, stream>>>(bsum, boff);
  k_scan3<<<grid_node, 256, 0, stream>>>(boff, startP, degcur);
  k_fill<<<grid_edges, 256, 0, stream>>>(ei, degcur, csr);
  k_pad<<<grid_node, 256, 0, stream>>>(degcur, startP, csr);

  // bf16 ping-pong: L0 xh0->xh1, L1 xh1->xh0, L2 xh0->xh1, final xh1->d_out
  k_gin<<<grid_mlp, 256, 0, stream>>>(xh0, startP, csr, eps, 0,
                                      W1, b1, W2, b2, xh1);
  k_gin<<<grid_mlp, 256, 0, stream>>>(xh1, startP, csr, eps, 1,
                                      W1 + 64 * 64, b1 + 64, W2 + 64 * 64, b2 + 64, xh0);
  k_gin<<<grid_mlp, 256, 0, stream>>>(xh0, startP, csr, eps, 2,
                                      W1 + 2 * 64 * 64, b1 + 2 * 64, W2 + 2 * 64 * 64, b2 + 2 * 64, xh1);
  k_final<<<grid_mlp, 256, 0, stream>>>(xh1, Wf, bf, (float*)d_out);
}